// Round 4
// baseline (271.398 us; speedup 1.0000x reference)
//
#include <hip/hip_runtime.h>
#include <math.h>

#define DIM    2048
#define NEXP   64
#define TPB    256
#define CH     32          // K elements per chunk (128 B per lane = one cache line)

typedef float f32x2  __attribute__((ext_vector_type(2)));
typedef float f32x4  __attribute__((ext_vector_type(4)));
typedef float f32x16 __attribute__((ext_vector_type(16)));

// one packed fp32 FMA: acc.{lo,hi} += x.{lo,hi} * w.{lo,hi}; W comes from SGPRs
#define PKFMA(ACC, XV, WV) \
    asm("v_pk_fma_f32 %0, %1, %2, %0" : "+v"(ACC) : "v"(XV), "s"(WV))

// ---------------- Kernel 1: partial logits, token-per-lane -------------------
// No LDS. x chunk lives in VGPRs (per-lane 128B line, MSHR-merged fetch).
// W address is wave-uniform -> s_load_dwordx16 -> SGPRs -> v_pk_fma_f32.
__device__ __forceinline__
void gemm_chunk(const f32x4 buf[8], const float* __restrict__ wb, f32x2 acc[NEXP]) {
    const f32x2* xp = (const f32x2*)buf;   // 16 k-pairs (constant-indexed, SROA'd)
#pragma unroll
    for (int e = 0; e < NEXP; ++e) {
        f32x16 w0 = *(const f32x16*)(wb + (size_t)e * DIM);        // k 0..15
        f32x16 w1 = *(const f32x16*)(wb + (size_t)e * DIM + 16);   // k 16..31
        const f32x2* wp0 = (const f32x2*)&w0;
        const f32x2* wp1 = (const f32x2*)&w1;
#pragma unroll
        for (int j = 0; j < 8; ++j) PKFMA(acc[e], xp[j],     wp0[j]);
#pragma unroll
        for (int j = 0; j < 8; ++j) PKFMA(acc[e], xp[8 + j], wp1[j]);
    }
}

__global__ __launch_bounds__(TPB, 2)
void router_part(const float* __restrict__ x, const float* __restrict__ Wg,
                 float* __restrict__ part, int n_tokens, int KC, int ks) {
    const int tid    = threadIdx.x;
    const int nblk_t = n_tokens / TPB;        // 64
    const int tb     = blockIdx.x % nblk_t;
    const int s      = blockIdx.x / nblk_t;
    const int k0     = s * KC;
    const int tok    = tb * TPB + tid;

    const float* xrow = x + (size_t)tok * DIM + k0;

    f32x2 acc[NEXP];
#pragma unroll
    for (int e = 0; e < NEXP; ++e) acc[e] = (f32x2)(0.f);

    f32x4 bufA[8], bufB[8];
#pragma unroll
    for (int q = 0; q < 8; ++q) bufA[q] = *(const f32x4*)(xrow + q * 4);

    const int nch = KC / CH;                  // even (8 for ks=8)
    for (int c = 0; c < nch; c += 2) {
        // prefetch chunk c+1 (always valid: c+1 <= nch-1)
        {
            const float* p1 = xrow + (c + 1) * CH;
#pragma unroll
            for (int q = 0; q < 8; ++q) bufB[q] = *(const f32x4*)(p1 + q * 4);
        }
        gemm_chunk(bufA, Wg + k0 + c * CH, acc);
        // prefetch chunk c+2 (guarded; uniform branch)
        if (c + 2 < nch) {
            const float* p2 = xrow + (c + 2) * CH;
#pragma unroll
            for (int q = 0; q < 8; ++q) bufA[q] = *(const f32x4*)(p2 + q * 4);
        }
        gemm_chunk(bufB, Wg + k0 + (c + 1) * CH, acc);
    }

    // store partials: part[token][s][e] (contiguous 2KB per token for finish)
    float* pb = part + ((size_t)tok * ks + s) * NEXP;
#pragma unroll
    for (int q = 0; q < 16; ++q) {
        f32x4 v;
        v.x = acc[q * 4 + 0].x + acc[q * 4 + 0].y;
        v.y = acc[q * 4 + 1].x + acc[q * 4 + 1].y;
        v.z = acc[q * 4 + 2].x + acc[q * 4 + 2].y;
        v.w = acc[q * 4 + 3].x + acc[q * 4 + 3].y;
        *(f32x4*)(pb + q * 4) = v;
    }
}

// ---------------- Kernel 2: reduce partials + softmax + top-2 + aux ----------
#define FTPB 64
__global__ __launch_bounds__(FTPB)
void router_finish(const float* __restrict__ part, float* __restrict__ out,
                   float* __restrict__ gCnt, float* __restrict__ gPsum,
                   int n_tokens, int ks) {
    __shared__ float pl[FTPB][NEXP + 1];
    __shared__ float cnt[NEXP];
    const int tid = threadIdx.x;
    const int tok = blockIdx.x * FTPB + tid;
    cnt[tid] = 0.f;                            // FTPB == NEXP
    __syncthreads();

    const float* pb = part + (size_t)tok * ks * NEXP;
    float lg[NEXP];
#pragma unroll
    for (int q = 0; q < 16; ++q) {
        f32x4 a = *(const f32x4*)(pb + q * 4);
        lg[q * 4 + 0] = a.x; lg[q * 4 + 1] = a.y;
        lg[q * 4 + 2] = a.z; lg[q * 4 + 3] = a.w;
    }
    for (int s2 = 1; s2 < ks; ++s2) {
#pragma unroll
        for (int q = 0; q < 16; ++q) {
            f32x4 a = *(const f32x4*)(pb + (size_t)s2 * NEXP + q * 4);
            lg[q * 4 + 0] += a.x; lg[q * 4 + 1] += a.y;
            lg[q * 4 + 2] += a.z; lg[q * 4 + 3] += a.w;
        }
    }

    // top-2 (strict > keeps lowest index on ties, matching lax.top_k)
    float m1 = -1e30f, m2 = -1e30f;
    int i1 = 0, i2 = 0;
#pragma unroll
    for (int e = 0; e < NEXP; ++e) {
        float l = lg[e];
        if (l > m1)      { m2 = m1; i2 = i1; m1 = l; i1 = e; }
        else if (l > m2) { m2 = l; i2 = e; }
    }

    float ssum = 0.f;
#pragma unroll
    for (int e = 0; e < NEXP; ++e) {
        float p = __expf(lg[e] - m1);
        lg[e] = p;
        ssum += p;
    }
    const float inv_s = 1.f / ssum;
#pragma unroll
    for (int e = 0; e < NEXP; ++e) pl[tid][e] = lg[e] * inv_s;

    const float p1 = inv_s;                    // exp(0)*inv_s
    const float p2 = __expf(m2 - m1) * inv_s;
    const float d  = p1 + p2 + 1e-8f;
    out[(size_t)tok * 2]     = (float)i1;
    out[(size_t)tok * 2 + 1] = (float)i2;
    out[(size_t)n_tokens * 2 + (size_t)tok * 2]     = p1 / d;
    out[(size_t)n_tokens * 2 + (size_t)tok * 2 + 1] = p2 / d;
    atomicAdd(&cnt[i1], 1.f);
    atomicAdd(&cnt[i2], 1.f);
    __syncthreads();

    // per-expert column sums of router_probs (thread e handles expert e)
    {
        float cs = 0.f;
#pragma unroll 8
        for (int t = 0; t < FTPB; ++t) cs += pl[t][tid];
        atomicAdd(&gPsum[tid], cs);
        atomicAdd(&gCnt[tid], cnt[tid]);
    }
}

// ---------------- Kernel 3: final aux loss -----------------------------------
__global__ void router_aux(const float* __restrict__ gCnt,
                           const float* __restrict__ gPsum,
                           float* __restrict__ out, int n_tokens) {
    const int e = threadIdx.x;
    float f = gCnt[e] / (float)(n_tokens * 2);
    float P = gPsum[e] / (float)n_tokens;
    float v = f * P;
#pragma unroll
    for (int o = 32; o > 0; o >>= 1) v += __shfl_down(v, o);
    if (e == 0) out[(size_t)n_tokens * 4] = 64.f * v;
}

extern "C" void kernel_launch(void* const* d_in, const int* in_sizes, int n_in,
                              void* d_out, int out_size, void* d_ws, size_t ws_size,
                              hipStream_t stream) {
    const float* x  = (const float*)d_in[0];
    const float* Wg = (const float*)d_in[1];
    float* out = (float*)d_out;
    const int n_tokens = in_sizes[0] / DIM;   // 16384

    // largest K-split whose partial buffer fits the workspace (ks=8 preferred:
    // 2 waves/SIMD occupancy; partials 33.5 MB)
    int ks = 8;
    while (ks > 1 &&
           (2 * NEXP + (size_t)ks * n_tokens * NEXP) * sizeof(float) > ws_size)
        ks >>= 1;
    const int KC = DIM / ks;

    float* gCnt  = (float*)d_ws;
    float* gPsum = gCnt + NEXP;
    float* partb = gPsum + NEXP;

    hipMemsetAsync(d_ws, 0, 2 * NEXP * sizeof(float), stream);
    hipLaunchKernelGGL(router_part, dim3((n_tokens / TPB) * ks), dim3(TPB), 0, stream,
                       x, Wg, partb, n_tokens, KC, ks);
    hipLaunchKernelGGL(router_finish, dim3(n_tokens / FTPB), dim3(FTPB), 0, stream,
                       partb, out, gCnt, gPsum, n_tokens, ks);
    hipLaunchKernelGGL(router_aux, dim3(1), dim3(NEXP), 0, stream,
                       gCnt, gPsum, out, n_tokens);
}

// Round 5
// 93.174 us; speedup vs baseline: 2.9128x; 2.9128x over previous
//
#include <hip/hip_runtime.h>
#include <math.h>

#define DIM    2048
#define NEXP   64
#define BM     128
#define BK     32
#define TPB    256
#define XPAD   132   // xT row stride (floats)
#define WPAD   66    // wT row stride (floats)

typedef float f32x4 __attribute__((ext_vector_type(4)));

// ---------------- Kernel 1: partial logits GEMM (fp32 vector FMA) ------------
// Block tile: 128 tokens x 64 experts, per-thread 4x8. LDS stores x,W
// TRANSPOSED [K][M] so inner reads are b128 along M (broadcast-dedup'd).
// Single-buffered LDS (25KB -> 4+ blocks/CU), reg-prefetch of next chunk.
__global__ __launch_bounds__(TPB)
void router_part(const float* __restrict__ x, const float* __restrict__ Wg,
                 float* __restrict__ part, int n_tokens, int ks) {
    __shared__ float xT[BK][XPAD];   // 16.9 KB
    __shared__ float wT[BK][WPAD];   //  8.4 KB

    const int tid   = threadIdx.x;
    const int nblkt = n_tokens / BM;            // 128
    const int tb    = blockIdx.x % nblkt;
    const int s     = blockIdx.x / nblkt;       // K-split index
    const int KC    = DIM / ks;
    const int k0    = s * KC;
    const int t0    = tb * BM;

    const int lo8 = tid & 7;                    // k-slot in staging / tc in compute
    const int hi  = tid >> 3;                   // 0..31: row group in staging / tr in compute

    float acc[4][8];
#pragma unroll
    for (int i = 0; i < 4; ++i)
#pragma unroll
        for (int j = 0; j < 8; ++j) acc[i][j] = 0.f;

    f32x4 px[4], pw[2];
    // prologue: load chunk 0
    {
        const float* xb = x + (size_t)t0 * DIM + k0 + lo8 * 4;
#pragma unroll
        for (int p = 0; p < 4; ++p)
            px[p] = *(const f32x4*)(xb + (size_t)(hi + 32 * p) * DIM);
        const float* wb = Wg + (size_t)0 * DIM + k0 + lo8 * 4;
#pragma unroll
        for (int q = 0; q < 2; ++q)
            pw[q] = *(const f32x4*)(wb + (size_t)(hi + 32 * q) * DIM);
    }

    const int nch = KC / BK;
    for (int c = 0; c < nch; ++c) {
        __syncthreads();   // previous chunk's compute done -> LDS reusable
        // stage chunk c from prefetch regs (transposed scatter, <=2-way writes)
#pragma unroll
        for (int p = 0; p < 4; ++p) {
            const int r = hi + 32 * p;
#pragma unroll
            for (int j = 0; j < 4; ++j) xT[lo8 * 4 + j][r] = px[p][j];
        }
#pragma unroll
        for (int q = 0; q < 2; ++q) {
            const int e = hi + 32 * q;
#pragma unroll
            for (int j = 0; j < 4; ++j) wT[lo8 * 4 + j][e] = pw[q][j];
        }
        // issue next chunk's global loads (in flight during compute)
        if (c + 1 < nch) {
            const int kb = k0 + (c + 1) * BK;
            const float* xb = x + (size_t)t0 * DIM + kb + lo8 * 4;
#pragma unroll
            for (int p = 0; p < 4; ++p)
                px[p] = *(const f32x4*)(xb + (size_t)(hi + 32 * p) * DIM);
            const float* wb = Wg + kb + lo8 * 4;
#pragma unroll
            for (int q = 0; q < 2; ++q)
                pw[q] = *(const f32x4*)(wb + (size_t)(hi + 32 * q) * DIM);
        }
        __syncthreads();   // staging visible
        // compute chunk c: per kk, 1+2 conflict-free b128 reads, 32 FMA
#pragma unroll
        for (int kk = 0; kk < BK; ++kk) {
            f32x4 xv = *(const f32x4*)&xT[kk][hi * 4];
            f32x4 w0 = *(const f32x4*)&wT[kk][lo8 * 8];
            f32x4 w1 = *(const f32x4*)&wT[kk][lo8 * 8 + 4];
#pragma unroll
            for (int i = 0; i < 4; ++i) {
#pragma unroll
                for (int j = 0; j < 4; ++j) {
                    acc[i][j]     = fmaf(xv[i], w0[j], acc[i][j]);
                    acc[i][4 + j] = fmaf(xv[i], w1[j], acc[i][4 + j]);
                }
            }
        }
    }

    // store partials: part[(tok*ks + s)*64 + e]
#pragma unroll
    for (int i = 0; i < 4; ++i) {
        const int t = t0 + hi * 4 + i;
        float* pb = part + ((size_t)t * ks + s) * NEXP + lo8 * 8;
        f32x4 v0, v1;
#pragma unroll
        for (int j = 0; j < 4; ++j) { v0[j] = acc[i][j]; v1[j] = acc[i][4 + j]; }
        *(f32x4*)(pb)     = v0;
        *(f32x4*)(pb + 4) = v1;
    }
}

// ---------------- Kernel 2: reduce partials + softmax + top-2 + aux ----------
#define FTPB 64
__global__ __launch_bounds__(FTPB)
void router_finish(const float* __restrict__ part, float* __restrict__ out,
                   float* __restrict__ gCnt, float* __restrict__ gPsum,
                   int n_tokens, int ks) {
    __shared__ float pl[FTPB][NEXP + 1];
    __shared__ float cnt[NEXP];
    const int tid = threadIdx.x;
    const int tok = blockIdx.x * FTPB + tid;
    cnt[tid] = 0.f;                            // FTPB == NEXP
    __syncthreads();

    const float* pb = part + (size_t)tok * ks * NEXP;
    float lg[NEXP];
#pragma unroll
    for (int q = 0; q < 16; ++q) {
        f32x4 a = *(const f32x4*)(pb + q * 4);
        lg[q * 4 + 0] = a.x; lg[q * 4 + 1] = a.y;
        lg[q * 4 + 2] = a.z; lg[q * 4 + 3] = a.w;
    }
    for (int s2 = 1; s2 < ks; ++s2) {
#pragma unroll
        for (int q = 0; q < 16; ++q) {
            f32x4 a = *(const f32x4*)(pb + (size_t)s2 * NEXP + q * 4);
            lg[q * 4 + 0] += a.x; lg[q * 4 + 1] += a.y;
            lg[q * 4 + 2] += a.z; lg[q * 4 + 3] += a.w;
        }
    }

    // top-2 (strict > keeps lowest index on ties, matching lax.top_k)
    float m1 = -1e30f, m2 = -1e30f;
    int i1 = 0, i2 = 0;
#pragma unroll
    for (int e = 0; e < NEXP; ++e) {
        float l = lg[e];
        if (l > m1)      { m2 = m1; i2 = i1; m1 = l; i1 = e; }
        else if (l > m2) { m2 = l; i2 = e; }
    }

    float ssum = 0.f;
#pragma unroll
    for (int e = 0; e < NEXP; ++e) {
        float p = __expf(lg[e] - m1);
        lg[e] = p;
        ssum += p;
    }
    const float inv_s = 1.f / ssum;
#pragma unroll
    for (int e = 0; e < NEXP; ++e) pl[tid][e] = lg[e] * inv_s;

    const float p1 = inv_s;                    // exp(0)*inv_s
    const float p2 = __expf(m2 - m1) * inv_s;
    const float d  = p1 + p2 + 1e-8f;
    out[(size_t)tok * 2]     = (float)i1;
    out[(size_t)tok * 2 + 1] = (float)i2;
    out[(size_t)n_tokens * 2 + (size_t)tok * 2]     = p1 / d;
    out[(size_t)n_tokens * 2 + (size_t)tok * 2 + 1] = p2 / d;
    atomicAdd(&cnt[i1], 1.f);
    atomicAdd(&cnt[i2], 1.f);
    __syncthreads();

    // per-expert column sums of router_probs (thread e handles expert e)
    {
        float cs = 0.f;
#pragma unroll 8
        for (int t = 0; t < FTPB; ++t) cs += pl[t][tid];
        atomicAdd(&gPsum[tid], cs);
        atomicAdd(&gCnt[tid], cnt[tid]);
    }
}

// ---------------- Kernel 3: final aux loss -----------------------------------
__global__ void router_aux(const float* __restrict__ gCnt,
                           const float* __restrict__ gPsum,
                           float* __restrict__ out, int n_tokens) {
    const int e = threadIdx.x;
    float f = gCnt[e] / (float)(n_tokens * 2);
    float P = gPsum[e] / (float)n_tokens;
    float v = f * P;
#pragma unroll
    for (int o = 32; o > 0; o >>= 1) v += __shfl_down(v, o);
    if (e == 0) out[(size_t)n_tokens * 4] = 64.f * v;
}

extern "C" void kernel_launch(void* const* d_in, const int* in_sizes, int n_in,
                              void* d_out, int out_size, void* d_ws, size_t ws_size,
                              hipStream_t stream) {
    const float* x  = (const float*)d_in[0];
    const float* Wg = (const float*)d_in[1];
    float* out = (float*)d_out;
    const int n_tokens = in_sizes[0] / DIM;   // 16384

    // largest K-split whose partial buffer fits the workspace
    int ks = 8;
    while (ks > 1 &&
           (2 * NEXP + (size_t)ks * n_tokens * NEXP) * sizeof(float) > ws_size)
        ks >>= 1;

    float* gCnt  = (float*)d_ws;
    float* gPsum = gCnt + NEXP;
    float* partb = gPsum + NEXP;

    hipMemsetAsync(d_ws, 0, 2 * NEXP * sizeof(float), stream);
    hipLaunchKernelGGL(router_part, dim3((n_tokens / BM) * ks), dim3(TPB), 0, stream,
                       x, Wg, partb, n_tokens, ks);
    hipLaunchKernelGGL(router_finish, dim3(n_tokens / FTPB), dim3(FTPB), 0, stream,
                       partb, out, gCnt, gPsum, n_tokens, ks);
    hipLaunchKernelGGL(router_aux, dim3(1), dim3(NEXP), 0, stream,
                       gCnt, gPsum, out, n_tokens);
}

// Round 6
// 87.657 us; speedup vs baseline: 3.0962x; 1.0629x over previous
//
#include <hip/hip_runtime.h>
#include <math.h>

#define DIM    2048
#define NEXP   64
#define BM     128
#define BK     32
#define TPB    256
#define XPAD   132   // x tile row stride (floats), mult-of-4, ≡4 mod 32
#define WPAD   68    // w tile row stride (floats), mult-of-4, ≡4 mod 32

typedef float f32x2 __attribute__((ext_vector_type(2)));
typedef float f32x4 __attribute__((ext_vector_type(4)));

// XOR swizzle (units of 4 floats). With row stride ≡4 (mod 32) this makes the
// transposed staging writes exactly 2 lanes/bank (free) for every wave while
// keeping compute reads conflict-free broadcasts and 16B alignment.
#define SW(k) ((((k) >> 1) & 7) << 2)

// ---------------- Kernel 1: partial logits GEMM (packed fp32 FMA) ------------
// Tile: 128 tokens x 64 experts, per-thread 4 tok x 8 exp. LDS holds x,W
// transposed [K][M], XOR-swizzled. Single-buffered LDS (25.6KB), register
// prefetch of next chunk issued before the compute phase.
__global__ __launch_bounds__(TPB)
void router_part(const float* __restrict__ x, const float* __restrict__ Wg,
                 float* __restrict__ part, int n_tokens, int ks) {
    __shared__ float xT[BK][XPAD];   // 16.9 KB
    __shared__ float wT[BK][WPAD];   //  8.7 KB

    const int tid   = threadIdx.x;
    const int nblkt = n_tokens / BM;            // 128
    const int tb    = blockIdx.x % nblkt;
    const int s     = blockIdx.x / nblkt;       // K-split index
    const int KC    = DIM / ks;
    const int k0    = s * KC;
    const int t0    = tb * BM;

    const int lo8 = tid & 7;                    // k-slot (stage) / expert octet (compute)
    const int hi  = tid >> 3;                   // 0..31: row group (stage) / token quad (compute)

    f32x2 acc[4][4];                            // [token i][expert pair jp]
#pragma unroll
    for (int i = 0; i < 4; ++i)
#pragma unroll
        for (int jp = 0; jp < 4; ++jp) acc[i][jp] = (f32x2)(0.f);

    f32x4 px[4], pw[2];
    {   // prologue: load chunk 0 (coalesced 128B per 8-lane group)
        const float* xb = x + (size_t)(t0 + hi) * DIM + k0 + lo8 * 4;
#pragma unroll
        for (int p = 0; p < 4; ++p)
            px[p] = *(const f32x4*)(xb + (size_t)(32 * p) * DIM);
        const float* wb = Wg + (size_t)hi * DIM + k0 + lo8 * 4;
#pragma unroll
        for (int q = 0; q < 2; ++q)
            pw[q] = *(const f32x4*)(wb + (size_t)(32 * q) * DIM);
    }

    const int nch = KC / BK;
    for (int c = 0; c < nch; ++c) {
        __syncthreads();   // previous chunk's compute done -> LDS reusable
        // transposed+swizzled scatter (all writes 2 lanes/bank = free)
#pragma unroll
        for (int j = 0; j < 4; ++j) {
            const int k  = lo8 * 4 + j;
            const int sw = SW(k);
#pragma unroll
            for (int p = 0; p < 4; ++p)
                xT[k][(hi + 32 * p) ^ sw] = px[p][j];
#pragma unroll
            for (int q = 0; q < 2; ++q)
                wT[k][(hi + 32 * q) ^ sw] = pw[q][j];
        }
        // issue next chunk's global loads (in flight across compute)
        if (c + 1 < nch) {
            const int kb = k0 + (c + 1) * BK;
            const float* xb = x + (size_t)(t0 + hi) * DIM + kb + lo8 * 4;
#pragma unroll
            for (int p = 0; p < 4; ++p)
                px[p] = *(const f32x4*)(xb + (size_t)(32 * p) * DIM);
            const float* wb = Wg + (size_t)hi * DIM + kb + lo8 * 4;
#pragma unroll
            for (int q = 0; q < 2; ++q)
                pw[q] = *(const f32x4*)(wb + (size_t)(32 * q) * DIM);
        }
        __syncthreads();   // staging visible
        // compute: per kk, 3 conflict-free b128 reads + 16 v_pk_fma_f32
#pragma unroll
        for (int kk = 0; kk < BK; ++kk) {
            const int sw = SW(kk);
            f32x4 xv = *(const f32x4*)&xT[kk][(hi * 4) ^ sw];
            f32x4 w0 = *(const f32x4*)&wT[kk][(lo8 * 8) ^ sw];
            f32x4 w1 = *(const f32x4*)&wT[kk][(lo8 * 8 + 4) ^ sw];
            f32x2 wp0 = {w0.x, w0.y}, wp1 = {w0.z, w0.w};
            f32x2 wp2 = {w1.x, w1.y}, wp3 = {w1.z, w1.w};
#pragma unroll
            for (int i = 0; i < 4; ++i) {
                f32x2 xb = {xv[i], xv[i]};
                acc[i][0] = __builtin_elementwise_fma(xb, wp0, acc[i][0]);
                acc[i][1] = __builtin_elementwise_fma(xb, wp1, acc[i][1]);
                acc[i][2] = __builtin_elementwise_fma(xb, wp2, acc[i][2]);
                acc[i][3] = __builtin_elementwise_fma(xb, wp3, acc[i][3]);
            }
        }
    }

    // store partials: part[(tok*ks + s)*64 + e], 2 x f32x4 per token
#pragma unroll
    for (int i = 0; i < 4; ++i) {
        const int t = t0 + hi * 4 + i;
        float* pb = part + ((size_t)t * ks + s) * NEXP + lo8 * 8;
        f32x4 v0, v1;
        v0.x = acc[i][0].x; v0.y = acc[i][0].y; v0.z = acc[i][1].x; v0.w = acc[i][1].y;
        v1.x = acc[i][2].x; v1.y = acc[i][2].y; v1.z = acc[i][3].x; v1.w = acc[i][3].y;
        *(f32x4*)(pb)     = v0;
        *(f32x4*)(pb + 4) = v1;
    }
}

// ---------------- Kernel 2: reduce partials + softmax + top-2 + aux ----------
#define FTPB 64
__global__ __launch_bounds__(FTPB)
void router_finish(const float* __restrict__ part, float* __restrict__ out,
                   float* __restrict__ gCnt, float* __restrict__ gPsum,
                   int n_tokens, int ks) {
    __shared__ float pl[FTPB][NEXP + 1];
    __shared__ float cnt[NEXP];
    const int tid = threadIdx.x;
    const int tok = blockIdx.x * FTPB + tid;
    cnt[tid] = 0.f;                            // FTPB == NEXP
    __syncthreads();

    const float* pb = part + (size_t)tok * ks * NEXP;
    float lg[NEXP];
#pragma unroll
    for (int q = 0; q < 16; ++q) {
        f32x4 a = *(const f32x4*)(pb + q * 4);
        lg[q * 4 + 0] = a.x; lg[q * 4 + 1] = a.y;
        lg[q * 4 + 2] = a.z; lg[q * 4 + 3] = a.w;
    }
    for (int s2 = 1; s2 < ks; ++s2) {
#pragma unroll
        for (int q = 0; q < 16; ++q) {
            f32x4 a = *(const f32x4*)(pb + (size_t)s2 * NEXP + q * 4);
            lg[q * 4 + 0] += a.x; lg[q * 4 + 1] += a.y;
            lg[q * 4 + 2] += a.z; lg[q * 4 + 3] += a.w;
        }
    }

    // top-2 (strict > keeps lowest index on ties, matching lax.top_k)
    float m1 = -1e30f, m2 = -1e30f;
    int i1 = 0, i2 = 0;
#pragma unroll
    for (int e = 0; e < NEXP; ++e) {
        float l = lg[e];
        if (l > m1)      { m2 = m1; i2 = i1; m1 = l; i1 = e; }
        else if (l > m2) { m2 = l; i2 = e; }
    }

    float ssum = 0.f;
#pragma unroll
    for (int e = 0; e < NEXP; ++e) {
        float p = __expf(lg[e] - m1);
        lg[e] = p;
        ssum += p;
    }
    const float inv_s = 1.f / ssum;
#pragma unroll
    for (int e = 0; e < NEXP; ++e) pl[tid][e] = lg[e] * inv_s;

    const float p1 = inv_s;                    // exp(0)*inv_s
    const float p2 = __expf(m2 - m1) * inv_s;
    const float d  = p1 + p2 + 1e-8f;
    out[(size_t)tok * 2]     = (float)i1;
    out[(size_t)tok * 2 + 1] = (float)i2;
    out[(size_t)n_tokens * 2 + (size_t)tok * 2]     = p1 / d;
    out[(size_t)n_tokens * 2 + (size_t)tok * 2 + 1] = p2 / d;
    atomicAdd(&cnt[i1], 1.f);
    atomicAdd(&cnt[i2], 1.f);
    __syncthreads();

    // per-expert column sums of router_probs (thread e handles expert e)
    {
        float cs = 0.f;
#pragma unroll 8
        for (int t = 0; t < FTPB; ++t) cs += pl[t][tid];
        atomicAdd(&gPsum[tid], cs);
        atomicAdd(&gCnt[tid], cnt[tid]);
    }
}

// ---------------- Kernel 3: final aux loss -----------------------------------
__global__ void router_aux(const float* __restrict__ gCnt,
                           const float* __restrict__ gPsum,
                           float* __restrict__ out, int n_tokens) {
    const int e = threadIdx.x;
    float f = gCnt[e] / (float)(n_tokens * 2);
    float P = gPsum[e] / (float)n_tokens;
    float v = f * P;
#pragma unroll
    for (int o = 32; o > 0; o >>= 1) v += __shfl_down(v, o);
    if (e == 0) out[(size_t)n_tokens * 4] = 64.f * v;
}

extern "C" void kernel_launch(void* const* d_in, const int* in_sizes, int n_in,
                              void* d_out, int out_size, void* d_ws, size_t ws_size,
                              hipStream_t stream) {
    const float* x  = (const float*)d_in[0];
    const float* Wg = (const float*)d_in[1];
    float* out = (float*)d_out;
    const int n_tokens = in_sizes[0] / DIM;   // 16384

    // largest K-split whose partial buffer fits the workspace
    int ks = 8;
    while (ks > 1 &&
           (2 * NEXP + (size_t)ks * n_tokens * NEXP) * sizeof(float) > ws_size)
        ks >>= 1;

    float* gCnt  = (float*)d_ws;
    float* gPsum = gCnt + NEXP;
    float* partb = gPsum + NEXP;

    hipMemsetAsync(d_ws, 0, 2 * NEXP * sizeof(float), stream);
    hipLaunchKernelGGL(router_part, dim3((n_tokens / BM) * ks), dim3(TPB), 0, stream,
                       x, Wg, partb, n_tokens, ks);
    hipLaunchKernelGGL(router_finish, dim3(n_tokens / FTPB), dim3(FTPB), 0, stream,
                       partb, out, gCnt, gPsum, n_tokens, ks);
    hipLaunchKernelGGL(router_aux, dim3(1), dim3(NEXP), 0, stream,
                       gCnt, gPsum, out, n_tokens);
}